// Round 3
// baseline (938.905 us; speedup 1.0000x reference)
//
#include <hip/hip_runtime.h>
#include <hip/hip_bf16.h>
#include <hip/hip_fp16.h>
#include <cstdint>

#define N_NODES 100000
#define N_EDGES 3200000
#define F_IN    512
#define F_HID   256
#define F_OUT   64
#define CAP     128   // slots/row; 512B line-aligned rows; Poisson(32) max ~65, huge margin

#define NSHARD   8          // one shard per XCD (blockIdx % 8 round-robins XCDs)
#define SHARD_SZ 12500      // N_NODES / NSHARD
#define G_SCATTER 12500     // N_EDGES / 256 exactly
#define LDS_STRIDE 272      // 544B row stride, 16B-aligned

typedef _Float16 half8_t __attribute__((ext_vector_type(8)));
typedef _Float16 half4_t __attribute__((ext_vector_type(4)));
typedef float    float4_t __attribute__((ext_vector_type(4)));

// packed ELL entry: bits [31:15] = col (<2^17), bits [14:0] = fp16 bits of val
// (val in [0,1) => sign bit 0 => fp16 fits in 15 bits, NO precision loss vs fp16)
__device__ __forceinline__ float unpack_val(unsigned p) {
    return (float)__builtin_bit_cast(_Float16, (unsigned short)(p & 0x7FFFu));
}

// ---------------- prep: zero cursors + W0/W1 -> fp16 transposed ----------------

__global__ __launch_bounds__(256) void prep_kernel(
    const float* __restrict__ W0, const float* __restrict__ W1,
    _Float16* __restrict__ W0T, _Float16* __restrict__ W1T,
    int* __restrict__ cursor) {
    int i = blockIdx.x * 256 + threadIdx.x;
    if (i < N_NODES) cursor[i] = 0;
    if (i < F_HID * F_IN) {                 // W0T[n][k] = W0[k][n], 256x512
        int n = i >> 9, k = i & 511;
        W0T[i] = (_Float16)W0[k * F_HID + n];
    }
    int j = i - F_HID * F_IN;
    if (j >= 0 && j < F_OUT * F_HID) {      // W1T[n][k] = W1[k][n], 64x256
        int n = j >> 8, k = j & 255;
        W1T[j] = (_Float16)W1[k * F_OUT + n];
    }
}

// ---------------- ELL scatter, XCD-affine sharding, packed 4B entries ----------------
// Blocks dispatch round-robin over the 8 XCDs (heuristic: xcd = blockIdx % 8).
// shard = blockIdx & 7 processes ONLY rows [12500*shard, 12500*(shard+1)) ->
// each ELL row is written by exactly ONE XCD: its line(s) stay in that XCD's L2,
// absorb all ~32 slot-writes, and write back once (vs per-edge partial-line HBM
// writes bouncing between incoherent L2s). Consecutive bids share the edge chunk
// (chunk = bid>>3) so the 8 shard-passes of a chunk read its lines ~concurrently.
// 4B packed entries: a 32-edge row spans ~1 cache line (rows are 512B-aligned).

__global__ __launch_bounds__(256) void ell_scatter_kernel(
    const int* __restrict__ erows, const int* __restrict__ ecols,
    const float* __restrict__ evals, int* __restrict__ cursor,
    unsigned* __restrict__ ell) {
    const int shard = blockIdx.x & 7;
    const int e = (blockIdx.x >> 3) * 256 + threadIdx.x;
    int r = erows[e];
    if (r / SHARD_SZ != shard) return;
    int p = atomicAdd(&cursor[r], 1);
    if (p < CAP) {
        unsigned short hb = __builtin_bit_cast(unsigned short, (_Float16)evals[e]);
        ell[(size_t)r * CAP + p] = ((unsigned)ecols[e] << 15) | (unsigned)hb;
    }
}

// ---------------- GEMM1: H0[M,256] = fp16(X[M,512] @ W0), row-major ----------------
// Block = 4 waves covers 64 m-rows x all 256 n (X read ONCE from HBM).
// Wave w covers n in [64w, 64w+64): 4x4 tiles of 16x16, K-step 32.
// Layouts (guide-verified): A[m=lane&15][k=quad*8+j]; B[k][n=lane&15];
// D: col(n)=lane&15, row(m)=quad*4+reg.

__global__ __launch_bounds__(256) void gemm1_mfma_kernel(
    const float* __restrict__ X, const _Float16* __restrict__ W0T,
    _Float16* __restrict__ H0) {
    const int wave = threadIdx.x >> 6;
    const int lane = threadIdx.x & 63;
    const int l15  = lane & 15;
    const int quad = lane >> 4;
    const int m0   = blockIdx.x * 64;
    const int n0   = wave * 64;

    float4_t acc[4][4] = {};   // [mt][nt]

    int row[4];
    #pragma unroll
    for (int mt = 0; mt < 4; mt++) {
        int r = m0 + mt * 16 + l15;
        row[mt] = r < N_NODES ? r : N_NODES - 1;  // clamp: garbage rows never stored
    }

    for (int k0 = 0; k0 < F_IN; k0 += 32) {
        const int kk = k0 + quad * 8;
        half8_t b[4];
        #pragma unroll
        for (int nt = 0; nt < 4; nt++)
            b[nt] = *(const half8_t*)(W0T + (size_t)(n0 + nt * 16 + l15) * F_IN + kk);

        half8_t a[4];
        #pragma unroll
        for (int mt = 0; mt < 4; mt++) {
            const float* p = X + (size_t)row[mt] * F_IN + kk;
            float4_t lo = *(const float4_t*)p;
            float4_t hi = *(const float4_t*)(p + 4);
            half8_t f;
            f[0] = (_Float16)lo[0]; f[1] = (_Float16)lo[1];
            f[2] = (_Float16)lo[2]; f[3] = (_Float16)lo[3];
            f[4] = (_Float16)hi[0]; f[5] = (_Float16)hi[1];
            f[6] = (_Float16)hi[2]; f[7] = (_Float16)hi[3];
            a[mt] = f;
        }

        #pragma unroll
        for (int mt = 0; mt < 4; mt++)
            #pragma unroll
            for (int nt = 0; nt < 4; nt++)
                acc[mt][nt] = __builtin_amdgcn_mfma_f32_16x16x32_f16(
                    a[mt], b[nt], acc[mt][nt], 0, 0, 0);
    }

    #pragma unroll
    for (int mt = 0; mt < 4; mt++)
        #pragma unroll
        for (int reg = 0; reg < 4; reg++) {
            int m = m0 + mt * 16 + quad * 4 + reg;
            if (m < N_NODES) {
                #pragma unroll
                for (int nt = 0; nt < 4; nt++)
                    H0[(size_t)m * F_HID + n0 + nt * 16 + l15] =
                        (_Float16)acc[mt][nt][reg];
            }
        }
}

// ---------------- SpMM layer 1 + ReLU + fused GEMM2 ----------------
// Block = 4 waves handles 16 rows. Phase 1: wave w gathers rows 4w..4w+3
// (wave-per-row, lane t = feats [4t,4t+4) -> one 512B coalesced wave-read per
// edge, fp32 accumulate), ReLU, stage fp16 rows in LDS.
// Phase 2: one 16x256 @ 256x64 MFMA tile: wave w computes classes [16w,16w+16).
// H1 never touches HBM.

__global__ __launch_bounds__(256) void spmm_relu_gemm2_kernel(
    const _Float16* __restrict__ H0, const unsigned* __restrict__ ell,
    const int* __restrict__ cursor, const _Float16* __restrict__ W1T,
    _Float16* __restrict__ H2) {
    __shared__ _Float16 hrow[16][LDS_STRIDE];

    const int wave = threadIdx.x >> 6;
    const int t    = threadIdx.x & 63;
    const int base = blockIdx.x * 16;     // 6250*16 == N_NODES exactly
    const half4_t* H0v = (const half4_t*)H0;   // unit = 4 feats

    for (int rr = 0; rr < 4; rr++) {
        const int local = wave * 4 + rr;
        const int r = base + local;
        int n = cursor[r]; if (n > CAP) n = CAP;
        const unsigned* cv = ell + (size_t)r * CAP;

        float4_t acc = {};
        int j = 0;
        for (; j + 4 <= n; j += 4) {
            uint4 e = *(const uint4*)(cv + j);    // 4 packed edges
            half4_t g0 = H0v[(size_t)(e.x >> 15) * 64 + t];
            half4_t g1 = H0v[(size_t)(e.y >> 15) * 64 + t];
            half4_t g2 = H0v[(size_t)(e.z >> 15) * 64 + t];
            half4_t g3 = H0v[(size_t)(e.w >> 15) * 64 + t];
            float v0 = unpack_val(e.x), v1 = unpack_val(e.y);
            float v2 = unpack_val(e.z), v3 = unpack_val(e.w);
            #pragma unroll
            for (int i = 0; i < 4; i++) {
                acc[i] = fmaf(v0, (float)g0[i], acc[i]);
                acc[i] = fmaf(v1, (float)g1[i], acc[i]);
                acc[i] = fmaf(v2, (float)g2[i], acc[i]);
                acc[i] = fmaf(v3, (float)g3[i], acc[i]);
            }
        }
        for (; j < n; j++) {
            unsigned e = cv[j];
            half4_t g = H0v[(size_t)(e >> 15) * 64 + t];
            float vv = unpack_val(e);
            #pragma unroll
            for (int i = 0; i < 4; i++) acc[i] = fmaf(vv, (float)g[i], acc[i]);
        }
        half4_t o;
        #pragma unroll
        for (int i = 0; i < 4; i++) o[i] = (_Float16)fmaxf(acc[i], 0.f);
        *(half4_t*)(&hrow[local][t * 4]) = o;
    }
    __syncthreads();

    // GEMM2 tile: D[16 rows][16 classes] per wave, K=256 in 8 steps
    const int l15  = t & 15;
    const int quad = t >> 4;
    float4_t acc2 = {};
    #pragma unroll
    for (int k0 = 0; k0 < F_HID; k0 += 32) {
        const int kk = k0 + quad * 8;
        half8_t a = *(const half8_t*)(&hrow[l15][kk]);   // A[m=l15][k]
        half8_t b = *(const half8_t*)(W1T + (size_t)(wave * 16 + l15) * F_HID + kk);
        acc2 = __builtin_amdgcn_mfma_f32_16x16x32_f16(a, b, acc2, 0, 0, 0);
    }
    #pragma unroll
    for (int reg = 0; reg < 4; reg++) {
        int m = base + quad * 4 + reg;
        H2[(size_t)m * F_OUT + wave * 16 + l15] = (_Float16)acc2[reg];
    }
}

// ---------------- SpMM layer 2 + fused softmax (packed ELL) ----------------

__global__ __launch_bounds__(256) void spmm_softmax_kernel(
    const _Float16* __restrict__ H2, const unsigned* __restrict__ ell,
    const int* __restrict__ cursor, float* __restrict__ out) {
    const int lane = threadIdx.x & 63;
    const int r = blockIdx.x * 4 + (threadIdx.x >> 6);
    int n = cursor[r]; if (n > CAP) n = CAP;
    const unsigned* cv = ell + (size_t)r * CAP;

    float acc = 0.f;
    int j = 0;
    for (; j + 4 <= n; j += 4) {
        uint4 e = *(const uint4*)(cv + j);
        acc = fmaf(unpack_val(e.x), (float)H2[(size_t)(e.x >> 15) * F_OUT + lane], acc);
        acc = fmaf(unpack_val(e.y), (float)H2[(size_t)(e.y >> 15) * F_OUT + lane], acc);
        acc = fmaf(unpack_val(e.z), (float)H2[(size_t)(e.z >> 15) * F_OUT + lane], acc);
        acc = fmaf(unpack_val(e.w), (float)H2[(size_t)(e.w >> 15) * F_OUT + lane], acc);
    }
    for (; j < n; j++) {
        unsigned e = cv[j];
        acc = fmaf(unpack_val(e), (float)H2[(size_t)(e >> 15) * F_OUT + lane], acc);
    }

    float m = acc;
    #pragma unroll
    for (int o = 32; o >= 1; o >>= 1) m = fmaxf(m, __shfl_xor(m, o, 64));
    float e = expf(acc - m);
    float s = e;
    #pragma unroll
    for (int o = 32; o >= 1; o >>= 1) s += __shfl_xor(s, o, 64);
    out[(size_t)r * F_OUT + lane] = e / s;
}

// ---------------- launcher ----------------

extern "C" void kernel_launch(void* const* d_in, const int* in_sizes, int n_in,
                              void* d_out, int out_size, void* d_ws, size_t ws_size,
                              hipStream_t stream) {
    const float* X     = (const float*)d_in[0];
    const int*   erows = (const int*)  d_in[1];
    const int*   ecols = (const int*)  d_in[2];
    const float* evals = (const float*)d_in[3];
    const float* W0    = (const float*)d_in[4];
    const float* W1    = (const float*)d_in[5];
    float* out = (float*)d_out;

    // workspace layout (all regions 16B-aligned); ~116 MB total
    char* p = (char*)d_ws;
    _Float16* H0  = (_Float16*)p; p += (size_t)N_NODES * F_HID * 2;   // 51.2 MB
    _Float16* H2  = (_Float16*)p; p += (size_t)N_NODES * F_OUT * 2;   // 12.8 MB
    _Float16* W0T = (_Float16*)p; p += (size_t)F_HID * F_IN * 2;      // 256 KB
    _Float16* W1T = (_Float16*)p; p += (size_t)F_OUT * F_HID * 2;     // 32 KB
    int*      cursor = (int*)p;   p += (size_t)N_NODES * 4;           // 0.4 MB
    unsigned* ell    = (unsigned*)p;                                  // 51.2 MB packed

    // 1. zero cursors + convert weights (576*256 == 147456 == exactly W0T+W1T elems)
    prep_kernel<<<576, 256, 0, stream>>>(W0, W1, W0T, W1T, cursor);

    // 2. ELL build, 8 XCD-affine row shards (each row written by one XCD's L2)
    ell_scatter_kernel<<<NSHARD * G_SCATTER, 256, 0, stream>>>(
        erows, ecols, evals, cursor, ell);

    // 3. H0 = fp16(X @ W0), row-major [N][256]
    gemm1_mfma_kernel<<<(N_NODES + 63) / 64, 256, 0, stream>>>(X, W0T, H0);

    // 4. H2 = fp16((relu(A @ H0)) @ W1)  -- H1 never touches HBM
    spmm_relu_gemm2_kernel<<<N_NODES / 16, 256, 0, stream>>>(H0, ell, cursor, W1T, H2);

    // 5. out = softmax(A @ H2)
    spmm_softmax_kernel<<<N_NODES / 4, 256, 0, stream>>>(H2, ell, cursor, out);
}

// Round 4
// 895.625 us; speedup vs baseline: 1.0483x; 1.0483x over previous
//
#include <hip/hip_runtime.h>
#include <hip/hip_bf16.h>
#include <hip/hip_fp16.h>
#include <cstdint>

#define N_NODES 100000
#define N_EDGES 3200000
#define F_IN    512
#define F_HID   256
#define F_OUT   64
#define CAP     96    // slots/row; Poisson(32) max over 100K rows ~65, 96 is safe

#define G_SCATTER 12500     // N_EDGES / 256 exactly
#define LDS_STRIDE 272      // 544B row stride, 16B-aligned

typedef _Float16 half8_t __attribute__((ext_vector_type(8)));
typedef _Float16 half4_t __attribute__((ext_vector_type(4)));
typedef float    float4_t __attribute__((ext_vector_type(4)));

// packed ELL entry: bits [31:15] = col (<2^17), bits [14:0] = fp16 bits of val
// (val in [0,1) => sign bit 0 => fp16 fits in 15 bits, NO precision loss vs fp16)
__device__ __forceinline__ float unpack_val(unsigned p) {
    return (float)__builtin_bit_cast(_Float16, (unsigned short)(p & 0x7FFFu));
}

// ---------------- prep: zero cursors + W0/W1 -> fp16 transposed ----------------

__global__ __launch_bounds__(256) void prep_kernel(
    const float* __restrict__ W0, const float* __restrict__ W1,
    _Float16* __restrict__ W0T, _Float16* __restrict__ W1T,
    int* __restrict__ cursor) {
    int i = blockIdx.x * 256 + threadIdx.x;
    if (i < N_NODES) cursor[i] = 0;
    if (i < F_HID * F_IN) {                 // W0T[n][k] = W0[k][n], 256x512
        int n = i >> 9, k = i & 511;
        W0T[i] = (_Float16)W0[k * F_HID + n];
    }
    int j = i - F_HID * F_IN;
    if (j >= 0 && j < F_OUT * F_HID) {      // W1T[n][k] = W1[k][n], 64x256
        int n = j >> 8, k = j & 255;
        W1T[j] = (_Float16)W1[k * F_OUT + n];
    }
}

// ---------------- ELL scatter: single pass, ONE 4B write per edge ----------------
// Sharding experiments (temporal r2, XCD-affine r3) were NULL: the cost is the
// number of dirty lines per edge (memory-side partial-line RMW), not L2 residency.
// r0 wrote 2 arrays (2 line-touches/edge, 290MB writeback); packed 4B entry = 1.

__global__ __launch_bounds__(256) void ell_scatter_kernel(
    const int* __restrict__ erows, const int* __restrict__ ecols,
    const float* __restrict__ evals, int* __restrict__ cursor,
    unsigned* __restrict__ ell) {
    const int e = blockIdx.x * 256 + threadIdx.x;   // grid covers N_EDGES exactly
    int r = erows[e];
    int p = atomicAdd(&cursor[r], 1);
    if (p < CAP) {
        unsigned short hb = __builtin_bit_cast(unsigned short, (_Float16)evals[e]);
        ell[(size_t)r * CAP + p] = ((unsigned)ecols[e] << 15) | (unsigned)hb;
    }
}

// ---------------- GEMM1: H0[M,256] = fp16(X[M,512] @ W0), row-major ----------------
// Block = 4 waves covers 64 m-rows x all 256 n (X read ONCE from HBM).
// Wave w covers n in [64w, 64w+64): 4x4 tiles of 16x16, K-step 32.
// Layouts (guide-verified): A[m=lane&15][k=quad*8+j]; B[k][n=lane&15];
// D: col(n)=lane&15, row(m)=quad*4+reg.

__global__ __launch_bounds__(256) void gemm1_mfma_kernel(
    const float* __restrict__ X, const _Float16* __restrict__ W0T,
    _Float16* __restrict__ H0) {
    const int wave = threadIdx.x >> 6;
    const int lane = threadIdx.x & 63;
    const int l15  = lane & 15;
    const int quad = lane >> 4;
    const int m0   = blockIdx.x * 64;
    const int n0   = wave * 64;

    float4_t acc[4][4] = {};   // [mt][nt]

    int row[4];
    #pragma unroll
    for (int mt = 0; mt < 4; mt++) {
        int r = m0 + mt * 16 + l15;
        row[mt] = r < N_NODES ? r : N_NODES - 1;  // clamp: garbage rows never stored
    }

    for (int k0 = 0; k0 < F_IN; k0 += 32) {
        const int kk = k0 + quad * 8;
        half8_t b[4];
        #pragma unroll
        for (int nt = 0; nt < 4; nt++)
            b[nt] = *(const half8_t*)(W0T + (size_t)(n0 + nt * 16 + l15) * F_IN + kk);

        half8_t a[4];
        #pragma unroll
        for (int mt = 0; mt < 4; mt++) {
            const float* p = X + (size_t)row[mt] * F_IN + kk;
            float4_t lo = *(const float4_t*)p;
            float4_t hi = *(const float4_t*)(p + 4);
            half8_t f;
            f[0] = (_Float16)lo[0]; f[1] = (_Float16)lo[1];
            f[2] = (_Float16)lo[2]; f[3] = (_Float16)lo[3];
            f[4] = (_Float16)hi[0]; f[5] = (_Float16)hi[1];
            f[6] = (_Float16)hi[2]; f[7] = (_Float16)hi[3];
            a[mt] = f;
        }

        #pragma unroll
        for (int mt = 0; mt < 4; mt++)
            #pragma unroll
            for (int nt = 0; nt < 4; nt++)
                acc[mt][nt] = __builtin_amdgcn_mfma_f32_16x16x32_f16(
                    a[mt], b[nt], acc[mt][nt], 0, 0, 0);
    }

    #pragma unroll
    for (int mt = 0; mt < 4; mt++)
        #pragma unroll
        for (int reg = 0; reg < 4; reg++) {
            int m = m0 + mt * 16 + quad * 4 + reg;
            if (m < N_NODES) {
                #pragma unroll
                for (int nt = 0; nt < 4; nt++)
                    H0[(size_t)m * F_HID + n0 + nt * 16 + l15] =
                        (_Float16)acc[mt][nt][reg];
            }
        }
}

// ---------------- SpMM layer 1 + ReLU + fused GEMM2, paired-edge gather ----------------
// Block = 4 waves handles 16 rows, wave-per-row. PAIRED gather: lanes 0-31 read
// edge A's 512B row (lane th: feats [8th,8th+8), one dwordx4), lanes 32-63 edge B
// -> each gather instruction moves 1024B (2 edges); 8-edge unrolled body keeps
// 4KB/wave in flight (r0/r3 had 4x512B). Halves accumulate disjoint edge subsets;
// one shfl_xor(32) per feat merges them. Then ReLU -> LDS -> 16x256 @ 256x64 MFMA
// (wave w: classes [16w,16w+16)). H1 never touches HBM.

__global__ __launch_bounds__(256) void spmm_relu_gemm2_kernel(
    const _Float16* __restrict__ H0, const unsigned* __restrict__ ell,
    const int* __restrict__ cursor, const _Float16* __restrict__ W1T,
    _Float16* __restrict__ H2) {
    __shared__ _Float16 hrow[16][LDS_STRIDE];

    const int wave = threadIdx.x >> 6;
    const int t    = threadIdx.x & 63;
    const int th   = t & 31;              // position within half-wave
    const int hi   = t >> 5;              // 0: even edge of pair, 1: odd edge
    const int base = blockIdx.x * 16;     // 6250*16 == N_NODES exactly
    const half8_t* H0v8 = (const half8_t*)H0;   // unit = 8 feats = 16B; row = 32 units

    for (int rr = 0; rr < 4; rr++) {
        const int local = wave * 4 + rr;
        const int r = base + local;
        int n = cursor[r]; if (n > CAP) n = CAP;
        const unsigned* cv = ell + (size_t)r * CAP;

        float acc[8] = {};   // feats [8th, 8th+8) over this half's edge subset
        int j = 0;
        for (; j + 8 <= n; j += 8) {
            uint4 ea = *(const uint4*)(cv + j);
            uint4 eb = *(const uint4*)(cv + j + 4);
            unsigned p0 = hi ? ea.y : ea.x;     // pair 0: edges j, j+1
            unsigned p1 = hi ? ea.w : ea.z;     // pair 1: edges j+2, j+3
            unsigned p2 = hi ? eb.y : eb.x;     // pair 2
            unsigned p3 = hi ? eb.w : eb.z;     // pair 3
            half8_t g0 = H0v8[(size_t)(p0 >> 15) * 32 + th];
            half8_t g1 = H0v8[(size_t)(p1 >> 15) * 32 + th];
            half8_t g2 = H0v8[(size_t)(p2 >> 15) * 32 + th];
            half8_t g3 = H0v8[(size_t)(p3 >> 15) * 32 + th];
            float v0 = unpack_val(p0), v1 = unpack_val(p1);
            float v2 = unpack_val(p2), v3 = unpack_val(p3);
            #pragma unroll
            for (int i = 0; i < 8; i++) {
                acc[i] = fmaf(v0, (float)g0[i], acc[i]);
                acc[i] = fmaf(v1, (float)g1[i], acc[i]);
                acc[i] = fmaf(v2, (float)g2[i], acc[i]);
                acc[i] = fmaf(v3, (float)g3[i], acc[i]);
            }
        }
        for (; j < n; j += 2) {               // tail: pad missing odd edge with v=0
            unsigned e0 = cv[j];
            unsigned e1 = (j + 1 < n) ? cv[j + 1] : e0;
            unsigned p  = hi ? e1 : e0;
            float vv = unpack_val(p);
            if (hi && j + 1 >= n) vv = 0.f;
            half8_t g = H0v8[(size_t)(p >> 15) * 32 + th];
            #pragma unroll
            for (int i = 0; i < 8; i++) acc[i] = fmaf(vv, (float)g[i], acc[i]);
        }

        // merge the two half-wave partial sums (lane th and th+32 own same feats)
        #pragma unroll
        for (int i = 0; i < 8; i++) acc[i] += __shfl_xor(acc[i], 32, 64);

        if (hi == 0) {
            half8_t o;
            #pragma unroll
            for (int i = 0; i < 8; i++) o[i] = (_Float16)fmaxf(acc[i], 0.f);
            *(half8_t*)(&hrow[local][th * 8]) = o;
        }
    }
    __syncthreads();

    // GEMM2 tile: D[16 rows][16 classes] per wave, K=256 in 8 steps
    const int l15  = t & 15;
    const int quad = t >> 4;
    float4_t acc2 = {};
    #pragma unroll
    for (int k0 = 0; k0 < F_HID; k0 += 32) {
        const int kk = k0 + quad * 8;
        half8_t a = *(const half8_t*)(&hrow[l15][kk]);   // A[m=l15][k]
        half8_t b = *(const half8_t*)(W1T + (size_t)(wave * 16 + l15) * F_HID + kk);
        acc2 = __builtin_amdgcn_mfma_f32_16x16x32_f16(a, b, acc2, 0, 0, 0);
    }
    #pragma unroll
    for (int reg = 0; reg < 4; reg++) {
        int m = base + quad * 4 + reg;
        H2[(size_t)m * F_OUT + wave * 16 + l15] = (_Float16)acc2[reg];
    }
}

// ---------------- SpMM layer 2 + fused softmax, 8-edge unroll ----------------

__global__ __launch_bounds__(256) void spmm_softmax_kernel(
    const _Float16* __restrict__ H2, const unsigned* __restrict__ ell,
    const int* __restrict__ cursor, float* __restrict__ out) {
    const int lane = threadIdx.x & 63;
    const int r = blockIdx.x * 4 + (threadIdx.x >> 6);
    int n = cursor[r]; if (n > CAP) n = CAP;
    const unsigned* cv = ell + (size_t)r * CAP;

    float acc = 0.f;
    int j = 0;
    for (; j + 8 <= n; j += 8) {            // 8 independent 2B gathers in flight
        uint4 ea = *(const uint4*)(cv + j);
        uint4 eb = *(const uint4*)(cv + j + 4);
        float h0 = (float)H2[(size_t)(ea.x >> 15) * F_OUT + lane];
        float h1 = (float)H2[(size_t)(ea.y >> 15) * F_OUT + lane];
        float h2 = (float)H2[(size_t)(ea.z >> 15) * F_OUT + lane];
        float h3 = (float)H2[(size_t)(ea.w >> 15) * F_OUT + lane];
        float h4 = (float)H2[(size_t)(eb.x >> 15) * F_OUT + lane];
        float h5 = (float)H2[(size_t)(eb.y >> 15) * F_OUT + lane];
        float h6 = (float)H2[(size_t)(eb.z >> 15) * F_OUT + lane];
        float h7 = (float)H2[(size_t)(eb.w >> 15) * F_OUT + lane];
        acc = fmaf(unpack_val(ea.x), h0, acc);
        acc = fmaf(unpack_val(ea.y), h1, acc);
        acc = fmaf(unpack_val(ea.z), h2, acc);
        acc = fmaf(unpack_val(ea.w), h3, acc);
        acc = fmaf(unpack_val(eb.x), h4, acc);
        acc = fmaf(unpack_val(eb.y), h5, acc);
        acc = fmaf(unpack_val(eb.z), h6, acc);
        acc = fmaf(unpack_val(eb.w), h7, acc);
    }
    for (; j < n; j++) {
        unsigned e = cv[j];
        acc = fmaf(unpack_val(e), (float)H2[(size_t)(e >> 15) * F_OUT + lane], acc);
    }

    float m = acc;
    #pragma unroll
    for (int o = 32; o >= 1; o >>= 1) m = fmaxf(m, __shfl_xor(m, o, 64));
    float e = expf(acc - m);
    float s = e;
    #pragma unroll
    for (int o = 32; o >= 1; o >>= 1) s += __shfl_xor(s, o, 64);
    out[(size_t)r * F_OUT + lane] = e / s;
}

// ---------------- launcher ----------------

extern "C" void kernel_launch(void* const* d_in, const int* in_sizes, int n_in,
                              void* d_out, int out_size, void* d_ws, size_t ws_size,
                              hipStream_t stream) {
    const float* X     = (const float*)d_in[0];
    const int*   erows = (const int*)  d_in[1];
    const int*   ecols = (const int*)  d_in[2];
    const float* evals = (const float*)d_in[3];
    const float* W0    = (const float*)d_in[4];
    const float* W1    = (const float*)d_in[5];
    float* out = (float*)d_out;

    // workspace layout (all regions 16B-aligned); ~103 MB total
    char* p = (char*)d_ws;
    _Float16* H0  = (_Float16*)p; p += (size_t)N_NODES * F_HID * 2;   // 51.2 MB
    _Float16* H2  = (_Float16*)p; p += (size_t)N_NODES * F_OUT * 2;   // 12.8 MB
    _Float16* W0T = (_Float16*)p; p += (size_t)F_HID * F_IN * 2;      // 256 KB
    _Float16* W1T = (_Float16*)p; p += (size_t)F_OUT * F_HID * 2;     // 32 KB
    int*      cursor = (int*)p;   p += (size_t)N_NODES * 4;           // 0.4 MB
    unsigned* ell    = (unsigned*)p;                                  // 38.4 MB packed

    // 1. zero cursors + convert weights (576*256 == 147456 == exactly W0T+W1T elems)
    prep_kernel<<<576, 256, 0, stream>>>(W0, W1, W0T, W1T, cursor);

    // 2. ELL build, single pass, one 4B write per edge
    ell_scatter_kernel<<<G_SCATTER, 256, 0, stream>>>(
        erows, ecols, evals, cursor, ell);

    // 3. H0 = fp16(X @ W0), row-major [N][256]
    gemm1_mfma_kernel<<<(N_NODES + 63) / 64, 256, 0, stream>>>(X, W0T, H0);

    // 4. H2 = fp16((relu(A @ H0)) @ W1)  -- H1 never touches HBM
    spmm_relu_gemm2_kernel<<<N_NODES / 16, 256, 0, stream>>>(H0, ell, cursor, W1T, H2);

    // 5. out = softmax(A @ H2)
    spmm_softmax_kernel<<<N_NODES / 4, 256, 0, stream>>>(H2, ell, cursor, out);
}